// Round 1
// 5240.821 us; speedup vs baseline: 1.2207x; 1.2207x over previous
//
#include <hip/hip_runtime.h>

typedef unsigned short u16;
typedef unsigned int u32;
typedef unsigned long long u64;
typedef __attribute__((ext_vector_type(8))) short short8;
typedef __attribute__((ext_vector_type(4))) float f32x4;

namespace {
constexpr int kS  = 256;
constexpr int kT  = 512;
constexpr int kNT = 100;
constexpr int LDST = 40;   // LDS row stride (bf16) for 32-wide K chunks (cat/gemm kernels)
}

__device__ __forceinline__ float bf(u16 v){ return __uint_as_float(((u32)v)<<16); }
__device__ __forceinline__ u16 f2bf(float f){
  u32 u = __float_as_uint(f);
  return (u16)((u + 0x7fffu + ((u>>16)&1u)) >> 16);
}
__device__ __forceinline__ float sigm(float x){ return 1.f/(1.f+__expf(-x)); }
__device__ __forceinline__ float tanha(float x){ return 2.f/(1.f+__expf(-2.f*x)) - 1.f; }
__device__ __forceinline__ float wred(float v){
  #pragma unroll
  for (int off=32; off>0; off>>=1) v += __shfl_xor(v, off, 64);
  return v;
}

// coherence-point (MALL) accesses: relaxed SYSTEM scope -> sc0 sc1, no wbl2/inv
__device__ __forceinline__ void st_sys_u32(void* p, u32 v){
  __hip_atomic_store((u32*)p, v, __ATOMIC_RELAXED, __HIP_MEMORY_SCOPE_SYSTEM);
}
__device__ __forceinline__ u32 ld_sys_u32(const void* p){
  return __hip_atomic_load((const u32*)p, __ATOMIC_RELAXED, __HIP_MEMORY_SCOPE_SYSTEM);
}

__global__ void k_zero(u32* p, int n){
  const int i = blockIdx.x*256 + threadIdx.x;
  if (i < n) p[i] = 0;
}

// ================= uniform persistent step kernel =================
// Each block owns 32 gate-cols (8 h-cols); Whh tile resident in LDS; c in LDS.
// h layout is slab-per-step (index s & 255): every h address is written exactly
// once per dispatch (system-scope store -> MALL before flag) and read only
// after its flag, so consumer reads can use NORMAL CACHED loads — each XCD's
// L2 holds one shared copy of h instead of 16 blocks each pulling it over the
// fabric at system scope. Flags stay at the coherence point, packed into one
// 256-B span so a poll round touches 4 lines, not 64.
struct SeqJob {
  u16* hseq;         // 131072-B slabs, slab index = s & 255
  const u16* xg; const int* idx;
  float* c_io;
  const u16* Bw;     // permuted Whh [2048][512]
  u32* flags;        // 64 contiguous u32
  int s_begin, s_end, mode, c_store;
};

__global__ __launch_bounds__(256,1) void k_seq2(SeqJob jA, SeqJob jB)
{
  __shared__ u16 Bs[32*520];          // 33.3 KB resident weight tile
  __shared__ float c_lds[128*9];      // block-private c columns
  __shared__ float sc[4*4*16*20];     // wave-private epilogue scratch
  const SeqJob j = (blockIdx.x < 64) ? jA : jB;
  const int gb = blockIdx.x & 63;
  const int tid = threadIdx.x;
  const int ln = tid & 63, w = tid >> 6, wm = w * 32;
  const int fr = ln & 15, koff = (ln >> 4) * 8;
  const int n0 = gb * 32, jh0 = gb * 8;

  for (int e = tid; e < 2048; e += 256) {
    const int cl = e >> 6, kb = (e & 63) * 8;
    *(uint4*)&Bs[cl*520 + kb] = *(const uint4*)&j.Bw[(size_t)(n0+cl)*512 + kb];
  }
  for (int e = tid; e < 1024; e += 256) {
    const int m = e >> 3, jj = e & 7;
    c_lds[m*9 + jj] = j.c_io[(size_t)m*512 + jh0 + jj];
  }
  __syncthreads();

  const size_t aoff0 = (size_t)(wm + fr)*512 + koff;
  const size_t aoff1 = (size_t)(wm + 16 + fr)*512 + koff;
  const int cr = (ln>>4)*4, cc = ln&15;
  const int trow = ln>>2, pp = ln&3, ntp = pp>>1, cp = pp&1;
  const f32x4 z4 = {0.f,0.f,0.f,0.f};

  for (int s = j.s_begin; s < j.s_end; ++s) {
    const u16* Ab = j.hseq + (size_t)((s-1)&255)*65536;
    u16* hout     = j.hseq + (size_t)(s&255)*65536;
    const u16* xgs = (j.mode == 0) ? (j.xg + (size_t)s*262144) : j.xg;

    // resolve xg rows first (mode-1 idx gather is a dependent load chain)
    int xrow[2];
    #pragma unroll
    for (int mt = 0; mt < 2; ++mt) {
      const int m = wm + mt*16 + trow;
      if (j.mode == 1)      xrow[mt] = j.idx[(size_t)m*512 + s];
      else if (j.mode == 0) xrow[mt] = m;
      else                  xrow[mt] = m*128 + s;
    }

    // h preload: plain cached loads (shared via the XCD's L2)
    uint4 aq0[16], aq1[16];
    #pragma unroll
    for (int kt = 0; kt < 16; ++kt) {
      aq0[kt] = *(const uint4*)&Ab[aoff0 + kt*32];
      aq1[kt] = *(const uint4*)&Ab[aoff1 + kt*32];
    }
    // xg gate preload for this step's epilogue (overlaps MFMA instead of
    // stalling serially inside the epilogue)
    uint4 xqv[2];
    #pragma unroll
    for (int mt = 0; mt < 2; ++mt)
      xqv[mt] = *(const uint4*)&xgs[(size_t)xrow[mt]*2048 + n0 + ntp*16 + cp*8];

    f32x4 acc[2][2] = {{z4,z4},{z4,z4}};
    #pragma unroll
    for (int kt = 0; kt < 16; ++kt) {
      union { uint4 q; short8 v; } ua, ub;
      ua.q = aq0[kt]; ub.q = aq1[kt];
      const short8 b0 = *(const short8*)&Bs[fr*520 + kt*32 + koff];
      const short8 b1 = *(const short8*)&Bs[(16+fr)*520 + kt*32 + koff];
      acc[0][0] = __builtin_amdgcn_mfma_f32_16x16x32_bf16(ua.v, b0, acc[0][0], 0,0,0);
      acc[0][1] = __builtin_amdgcn_mfma_f32_16x16x32_bf16(ua.v, b1, acc[0][1], 0,0,0);
      acc[1][0] = __builtin_amdgcn_mfma_f32_16x16x32_bf16(ub.v, b0, acc[1][0], 0,0,0);
      acc[1][1] = __builtin_amdgcn_mfma_f32_16x16x32_bf16(ub.v, b1, acc[1][1], 0,0,0);
    }

    // epilogue: wave-private transpose via LDS
    #pragma unroll
    for (int mt=0; mt<2; ++mt)
      #pragma unroll
      for (int nt=0; nt<2; ++nt) {
        float* scb = &sc[(size_t)(w*4 + mt*2 + nt)*320];
        #pragma unroll
        for (int ri=0; ri<4; ++ri) scb[(cr+ri)*20 + cc] = acc[mt][nt][ri];
      }
    // gates: each lane produces 2 adjacent h cols -> one packed u32 store
    #pragma unroll
    for (int mt=0; mt<2; ++mt) {
      const int m = wm + mt*16 + trow;
      const float* scb = &sc[(size_t)(w*4+mt*2+ntp)*320 + trow*20 + cp*8];
      const float4 zlo = *(const float4*)&scb[0];
      const float4 zhi = *(const float4*)&scb[4];
      union { uint4 u4; u16 h[8]; } xq;
      xq.u4 = xqv[mt];
      const int cj = m*9 + ntp*4 + cp*2;
      float h0, h1;
      {
        const float i_ = sigm(zlo.x + bf(xq.h[0]));
        const float f_ = sigm(zlo.y + bf(xq.h[1]));
        const float g_ = tanha(zlo.z + bf(xq.h[2]));
        const float o_ = sigm(zlo.w + bf(xq.h[3]));
        const float cn = f_*c_lds[cj] + i_*g_;
        c_lds[cj] = cn;
        h0 = o_*tanha(cn);
      }
      {
        const float i_ = sigm(zhi.x + bf(xq.h[4]));
        const float f_ = sigm(zhi.y + bf(xq.h[5]));
        const float g_ = tanha(zhi.z + bf(xq.h[6]));
        const float o_ = sigm(zhi.w + bf(xq.h[7]));
        const float cn = f_*c_lds[cj+1] + i_*g_;
        c_lds[cj+1] = cn;
        h1 = o_*tanha(cn);
      }
      const u32 pk = (u32)f2bf(h0) | ((u32)f2bf(h1) << 16);
      st_sys_u32(&hout[(size_t)m*512 + jh0 + ntp*4 + cp*2], pk);
    }

    // ---- fence-free sync: drain to coherence point, signal, poll ----
    __builtin_amdgcn_s_waitcnt(0);
    __syncthreads();
    if (tid == 0)
      st_sys_u32(j.flags + gb, (u32)s);
    if (s + 1 < j.s_end) {
      if (tid < 64) {
        while (true) {
          u32 f = ld_sys_u32(j.flags + tid);
          if (__all((int)(f >= (u32)s))) break;
          __builtin_amdgcn_s_sleep(1);
        }
      }
      __syncthreads();
    }
  }
  if (j.c_store) {
    __syncthreads();
    for (int e = tid; e < 1024; e += 256) {
      const int m = e >> 3, jj = e & 7;
      j.c_io[(size_t)m*512 + jh0 + jj] = c_lds[m*9 + jj];
    }
  }
}

// ---------------- shared MFMA K-loop core (linear A): 128x128 C-tile, BK=32 ----------------
__device__ __forceinline__ void gemm_core(
    const u16* __restrict__ A, const u16* __restrict__ B, int K,
    int m0, int n0, u16* As, u16* Bs, f32x4 acc[4][4], int tid)
{
  const int lane = tid & 63;
  const int w = tid >> 6;
  const int wm = (w & 1) * 64, wn = (w >> 1) * 64;
  const int fr = lane & 15;
  const int fq = (lane >> 4) * 8;
  for (int k0 = 0; k0 < K; k0 += 32) {
    __syncthreads();
    #pragma unroll
    for (int it = 0; it < 2; ++it) {
      const int l = tid + it * 256;
      const int r = l >> 2, kq = (l & 3) * 8;
      *(uint4*)&As[r * LDST + kq] = *(const uint4*)&A[(size_t)(m0 + r) * K + k0 + kq];
      *(uint4*)&Bs[r * LDST + kq] = *(const uint4*)&B[(size_t)(n0 + r) * K + k0 + kq];
    }
    __syncthreads();
    short8 af[4], bfr[4];
    #pragma unroll
    for (int t = 0; t < 4; ++t) {
      af[t]  = *(const short8*)&As[(wm + t * 16 + fr) * LDST + fq];
      bfr[t] = *(const short8*)&Bs[(wn + t * 16 + fr) * LDST + fq];
    }
    #pragma unroll
    for (int mt = 0; mt < 4; ++mt)
      #pragma unroll
      for (int nt = 0; nt < 4; ++nt)
        acc[mt][nt] = __builtin_amdgcn_mfma_f32_16x16x32_bf16(af[mt], bfr[nt], acc[mt][nt], 0, 0, 0);
  }
}

// ---------------- plain GEMM: C = A @ B^T (+bias) (opt tanh), C bf16 ----------------
__global__ __launch_bounds__(256) void k_gemm(
    const u16* __restrict__ A, const u16* __restrict__ B, u16* __restrict__ C,
    const float* __restrict__ bias, int K, int N, int tanh_flag)
{
  __shared__ u16 As[128 * LDST];
  __shared__ u16 Bs[128 * LDST];
  const int tid = threadIdx.x;
  const int m0 = blockIdx.x * 128, n0 = blockIdx.y * 128;
  f32x4 acc[4][4];
  const f32x4 z4 = {0.f, 0.f, 0.f, 0.f};
  #pragma unroll
  for (int mt = 0; mt < 4; ++mt)
    #pragma unroll
    for (int nt = 0; nt < 4; ++nt) acc[mt][nt] = z4;

  gemm_core(A, B, K, m0, n0, As, Bs, acc, tid);

  const int lane = tid & 63;
  const int w = tid >> 6;
  const int wm = (w & 1) * 64, wn = (w >> 1) * 64;
  const int cr = (lane >> 4) * 4, cc = lane & 15;
  #pragma unroll
  for (int mt = 0; mt < 4; ++mt)
    #pragma unroll
    for (int nt = 0; nt < 4; ++nt)
      #pragma unroll
      for (int ri = 0; ri < 4; ++ri) {
        const int row = m0 + wm + mt * 16 + cr + ri;
        const int col = n0 + wn + nt * 16 + cc;
        float v = acc[mt][nt][ri];
        if (bias) v += bias[col];
        if (tanh_flag) v = tanha(v);
        C[(size_t)row * N + col] = f2bf(v);
      }
}

// ---------------- fused concat-K step (one step, many rows): reduce steps 2/3 ----------------
__global__ __launch_bounds__(256) void k_lstm_cat(
    const u16* __restrict__ H, const u16* __restrict__ X,
    const u16* __restrict__ B, const float* __restrict__ bias,
    const int* __restrict__ idx, int cmode, int p0, int first,
    float* __restrict__ c_st, u16* __restrict__ h_out, int h_stride, int h_coloff)
{
  __shared__ u16 As[128 * LDST];
  __shared__ u16 Bs[128 * LDST];
  __shared__ float zb[64 * 128];
  const int tid = threadIdx.x;
  const int m0 = blockIdx.x * 128, n0 = blockIdx.y * 128;
  const int lane = tid & 63;
  const int w = tid >> 6;
  const int wm = (w & 1) * 64, wn = (w >> 1) * 64;
  const int fr = lane & 15, fq = (lane >> 4) * 8;
  f32x4 acc[4][4];
  const f32x4 z4 = {0.f, 0.f, 0.f, 0.f};
  #pragma unroll
  for (int mt = 0; mt < 4; ++mt)
    #pragma unroll
    for (int nt = 0; nt < 4; ++nt) acc[mt][nt] = z4;

  for (int k0 = first ? 512 : 0; k0 < 1024; k0 += 32) {
    __syncthreads();
    #pragma unroll
    for (int it = 0; it < 2; ++it) {
      const int l = tid + it * 256;
      const int r = l >> 2, kq = (l & 3) * 8;
      const int m = m0 + r;
      const u16* src;
      if (k0 < 512) {
        src = H + (size_t)m * 512 + k0 + kq;
      } else {
        long xr;
        if (cmode == 1)      xr = (long)(2 * (m & 127) + p0) * 128 + (m >> 7);
        else if (cmode == 2) xr = (long)idx[m];
        else                 xr = (long)m * 128 + p0;
        src = X + (size_t)xr * 512 + (k0 - 512) + kq;
      }
      *(uint4*)&As[r * LDST + kq] = *(const uint4*)src;
      *(uint4*)&Bs[r * LDST + kq] = *(const uint4*)&B[(size_t)(n0 + r) * 1024 + k0 + kq];
    }
    __syncthreads();
    short8 af[4], bfr[4];
    #pragma unroll
    for (int t = 0; t < 4; ++t) {
      af[t]  = *(const short8*)&As[(wm + t * 16 + fr) * LDST + fq];
      bfr[t] = *(const short8*)&Bs[(wn + t * 16 + fr) * LDST + fq];
    }
    #pragma unroll
    for (int mt = 0; mt < 4; ++mt)
      #pragma unroll
      for (int nt = 0; nt < 4; ++nt)
        acc[mt][nt] = __builtin_amdgcn_mfma_f32_16x16x32_bf16(af[mt], bfr[nt], acc[mt][nt], 0, 0, 0);
  }

  const int cr = (lane >> 4) * 4, cc = lane & 15;
  #pragma unroll
  for (int half = 0; half < 2; ++half) {
    __syncthreads();
    if (wm == half * 64) {
      #pragma unroll
      for (int mt = 0; mt < 4; ++mt)
        #pragma unroll
        for (int nt = 0; nt < 4; ++nt)
          #pragma unroll
          for (int ri = 0; ri < 4; ++ri)
            zb[(mt * 16 + cr + ri) * 128 + wn + nt * 16 + cc] = acc[mt][nt][ri];
    }
    __syncthreads();
    for (int c = tid; c < 2048; c += 256) {
      const int rl = c >> 5;
      const int q  = c & 31;
      const int m  = m0 + half * 64 + rl;
      const int jh = (n0 >> 2) + q;
      const float4 bv = *(const float4*)&bias[n0 + q * 4];
      const float4 zv = *(const float4*)&zb[rl * 128 + q * 4];
      const float i_ = sigm(zv.x + bv.x);
      const float f_ = sigm(zv.y + bv.y);
      const float g_ = tanha(zv.z + bv.z);
      const float o_ = sigm(zv.w + bv.w);
      const size_t ci = (size_t)m * 512 + jh;
      const float cold = first ? 0.f : c_st[ci];
      const float cn = f_ * cold + i_ * g_;
      c_st[ci] = cn;
      h_out[(size_t)m * h_stride + h_coloff + jh] = f2bf(o_ * tanha(cn));
    }
  }
}

// ---------------- first LSTM step from XG table (no h) ----------------
__global__ __launch_bounds__(256) void k_gate0(
    const u16* __restrict__ xg, int xg_mode, int p0,
    const int* __restrict__ idx, int istride,
    float* __restrict__ c_st, u16* __restrict__ h_out, int h_stride, int h_coloff, int M)
{
  const int id = blockIdx.x * 256 + threadIdx.x;
  if (id >= M * 512) return;
  const int m = id >> 9, jh = id & 511;
  long xr;
  if (xg_mode == 0) xr = (long)m * p0;
  else              xr = (long)idx[(size_t)m * istride];
  const ushort4 xq = *(const ushort4*)&xg[(size_t)xr * 2048 + jh * 4];
  const float i_ = sigm(bf(xq.x));
  const float g_ = tanha(bf(xq.z));
  const float o_ = sigm(bf(xq.w));
  const float cn = i_ * g_;
  c_st[(size_t)m * 512 + jh] = cn;
  h_out[(size_t)m * h_stride + h_coloff + jh] = f2bf(o_ * tanha(cn));
}

// ---------------- preps ----------------
__global__ void k_perm_w(const float* __restrict__ in, u16* __restrict__ out,
                         int Ksrc, int Kfill, int Ktot, int coff)
{
  const int rp = blockIdx.x;             // 0..2047
  const int g = rp & 3, jh = rp >> 2;
  const float* src = in + (size_t)(g * 512 + jh) * Ksrc;
  for (int k = threadIdx.x; k < Kfill; k += 256)
    out[(size_t)rp * Ktot + coff + k] = f2bf(k < Ksrc ? src[k] : 0.f);
}
__global__ void k_perm_b(const float* __restrict__ in, float* __restrict__ out)
{
  const int rp = blockIdx.x * 256 + threadIdx.x;
  out[rp] = in[(rp & 3) * 512 + (rp >> 2)];
}
__global__ void k_cvt(const float* __restrict__ in, u16* __restrict__ out, int n)
{
  const int i = blockIdx.x * 256 + threadIdx.x;
  if (i < n) out[i] = f2bf(in[i]);
}
__global__ void k_pad2d(const float* __restrict__ in, u16* __restrict__ out,
                        int Rin, int Kin, int Kout)
{
  const int r = blockIdx.x;
  for (int k = threadIdx.x; k < Kout; k += 256)
    out[(size_t)r * Kout + k] = f2bf((r < Rin && k < Kin) ? in[(size_t)r * Kin + k] : 0.f);
}
__global__ void k_gather_word(const int* __restrict__ widx, const int* __restrict__ tidx,
                              const float* __restrict__ emb, const float* __restrict__ temb,
                              u16* __restrict__ Aw)
{
  const int row = blockIdx.x;            // 0..32767 = s*128+b
  const int s = row >> 7, b = row & 127;
  const int wi = widx[b * kS + s];
  const int ti = tidx[b * kS + s];
  for (int t = threadIdx.x; t < 320; t += 256)
    Aw[(size_t)row * 320 + t] = f2bf(t < 300 ? emb[(size_t)wi * 300 + t] : temb[ti * 20 + t - 300]);
}

// ---------------- out = [word_h_last | tr_h | con_h] @ W^T + b ----------------
__global__ __launch_bounds__(256) void k_out(
    const u16* __restrict__ wh, const u16* __restrict__ trh, const u16* __restrict__ conh,
    const float* __restrict__ W, const float* __restrict__ bias, float* __restrict__ out)
{
  const int wid = blockIdx.x * 4 + (threadIdx.x >> 6);
  const int lane = threadIdx.x & 63;
  const int b = wid / kNT;
  const int t = wid - b * kNT;
  const u16* s0 = wh + (size_t)b * 512;
  const u16* s1 = trh + (size_t)b * 512;
  const u16* s2 = conh + (size_t)b * 512;
  const float* wr = W + (size_t)t * 1536;
  float acc = 0.f;
  #pragma unroll
  for (int i = 0; i < 8; ++i) acc += bf(s0[i * 64 + lane]) * wr[i * 64 + lane];
  #pragma unroll
  for (int i = 0; i < 8; ++i) acc += bf(s1[i * 64 + lane]) * wr[512 + i * 64 + lane];
  #pragma unroll
  for (int i = 0; i < 8; ++i) acc += bf(s2[i * 64 + lane]) * wr[1024 + i * 64 + lane];
  acc = wred(acc);
  if (lane == 0) out[(size_t)b * kNT + t] = acc + bias[t];
}

extern "C" void kernel_launch(void* const* d_in, const int* in_sizes, int n_in,
                              void* d_out, int out_size, void* d_ws, size_t ws_size,
                              hipStream_t stream)
{
  (void)in_sizes; (void)n_in; (void)out_size; (void)ws_size;
  const int* word_idx = (const int*)d_in[0];
  const int* tag_idx  = (const int*)d_in[1];
  const int* tr_idx   = (const int*)d_in[2];
  const int* lab_idx  = (const int*)d_in[3];
  const float* emb       = (const float*)d_in[4];
  const float* tag_emb   = (const float*)d_in[5];
  const float* tr_emb    = (const float*)d_in[6];
  const float* const_emb = (const float*)d_in[7];
  const float* word_Wih = (const float*)d_in[8];
  const float* word_Whh = (const float*)d_in[9];
  const float* word_b   = (const float*)d_in[10];
  const float* tr_Wih = (const float*)d_in[11];
  const float* tr_Whh = (const float*)d_in[12];
  const float* tr_b   = (const float*)d_in[13];
  const float* con_Wih = (const float*)d_in[14];
  const float* con_Whh = (const float*)d_in[15];
  const float* con_b   = (const float*)d_in[16];
  const float* fwd_Wih = (const float*)d_in[17];
  const float* fwd_Whh = (const float*)d_in[18];
  const float* fwd_b   = (const float*)d_in[19];
  const float* bwd_Wih = (const float*)d_in[20];
  const float* bwd_Whh = (const float*)d_in[21];
  const float* bwd_b   = (const float*)d_in[22];
  const float* w2c_W = (const float*)d_in[23];
  const float* w2c_b = (const float*)d_in[24];
  const float* red_W = (const float*)d_in[25];
  const float* red_b = (const float*)d_in[26];
  const float* out_W = (const float*)d_in[27];
  const float* out_b = (const float*)d_in[28];

  char* p = (char*)d_ws;
  auto alloc = [&](size_t bytes)->void* {
    void* r = (void*)p; p += (bytes + 255) & ~(size_t)255; return r;
  };
  // -------- arena (~227 MB; phase-aliased big region) --------
  // word_h: 256 slabs of 131072 B (slab s = step s h), whole run
  u16* word_h = (u16*)alloc((size_t)33554432);
  char* R     = (char*)alloc((size_t)167772160);         // 167.8 MB aliased region
  // prep phase:
  u16* A_word = (u16*)(R);                               // 21.0 MB, dead after XGword gemm
  u16* XGword = (u16*)(R + 33554432);                    // 134.2 MB, dead after launch 1
  // launch 1 + 2: transition h slab ring (256 slabs), slabs 0..254 reusable as
  // scratch between launches (only slab 255 must survive into launch 2)
  u16* trseq  = (u16*)(R);                               // 33.55 MB
  // reduce phase (over dead XGword):
  u16* c0     = (u16*)(R + 33554432);                    // 33.55
  u16* h1     = (u16*)(R + 67108864);                    // 16.8
  u16* h2     = (u16*)(R + 83886080);                    // 16.8
  float* c_big= (float*)(R + 100663296);                 // 33.55
  u16* fb     = (u16*)(R + 134217728);                   // 33.55
  u16* red    = (u16*)(R);                               // 16.8 over trseq slabs 0..127 (dead)
  u16* XG_con = (u16*)(R + 67108864);                    // 67.1 (h1/h2/c_big dead)
  u16* conseq = (u16*)(R + 134217728);                   // 16.8, 128 slabs (fb dead)
  // weights / small (persistent)
  u16* wWih = (u16*)alloc((size_t)2048*320*2);
  u16* wWhh = (u16*)alloc((size_t)2048*512*2);
  u16* tWih = (u16*)alloc((size_t)2048*32*2);
  u16* tWhh = (u16*)alloc((size_t)2048*512*2);
  u16* cWihp = (u16*)alloc((size_t)2048*512*2);
  u16* cWhhp = (u16*)alloc((size_t)2048*512*2);
  u16* fWcat = (u16*)alloc((size_t)2048*1024*2);
  u16* bWcat = (u16*)alloc((size_t)2048*1024*2);
  u16* fWih  = (u16*)alloc((size_t)2048*512*2);
  u16* bWih  = (u16*)alloc((size_t)2048*512*2);
  u16* w2cWb = (u16*)alloc((size_t)512*512*2);
  u16* redWb = (u16*)alloc((size_t)512*1024*2);
  u16* A80   = (u16*)alloc((size_t)128*512*2);
  u16* Atr   = (u16*)alloc((size_t)128*32*2);
  u16* tbltr = (u16*)alloc((size_t)128*2048*2);
  u16* tbl0  = (u16*)alloc((size_t)128*2048*2);
  float* b_word = (float*)alloc(2048*4);
  float* b_tr   = (float*)alloc(2048*4);
  float* b_con  = (float*)alloc(2048*4);
  float* b_fwd  = (float*)alloc(2048*4);
  float* b_bwd  = (float*)alloc(2048*4);
  float* c_word = (float*)alloc((size_t)128*512*4);
  float* c_tr   = (float*)alloc((size_t)128*512*4);
  float* c_con  = (float*)alloc((size_t)128*512*4);
  u32* flags = (u32*)alloc((size_t)4*64*4);   // 4 groups x 64 packed flags

  // ---- init ----
  k_zero<<<1,256,0,stream>>>(flags, 4*64);

  // ---- preps ----
  k_perm_w<<<2048,256,0,stream>>>(word_Wih, wWih, 320, 320, 320, 0);
  k_perm_w<<<2048,256,0,stream>>>(word_Whh, wWhh, 512, 512, 512, 0);
  k_perm_w<<<2048,256,0,stream>>>(tr_Wih,   tWih, 20,  32,  32,  0);
  k_perm_w<<<2048,256,0,stream>>>(tr_Whh,   tWhh, 512, 512, 512, 0);
  k_perm_w<<<2048,256,0,stream>>>(con_Wih,  cWihp, 512, 512, 512, 0);
  k_perm_w<<<2048,256,0,stream>>>(con_Whh,  cWhhp, 512, 512, 512, 0);
  k_perm_w<<<2048,256,0,stream>>>(fwd_Whh,  fWcat, 512, 512, 1024, 0);
  k_perm_w<<<2048,256,0,stream>>>(fwd_Wih,  fWcat, 512, 512, 1024, 512);
  k_perm_w<<<2048,256,0,stream>>>(bwd_Whh,  bWcat, 512, 512, 1024, 0);
  k_perm_w<<<2048,256,0,stream>>>(bwd_Wih,  bWcat, 512, 512, 1024, 512);
  k_perm_w<<<2048,256,0,stream>>>(fwd_Wih,  fWih, 512, 512, 512, 0);
  k_perm_w<<<2048,256,0,stream>>>(bwd_Wih,  bWih, 512, 512, 512, 0);
  k_perm_b<<<8,256,0,stream>>>(word_b, b_word);
  k_perm_b<<<8,256,0,stream>>>(tr_b,   b_tr);
  k_perm_b<<<8,256,0,stream>>>(con_b,  b_con);
  k_perm_b<<<8,256,0,stream>>>(fwd_b,  b_fwd);
  k_perm_b<<<8,256,0,stream>>>(bwd_b,  b_bwd);
  k_cvt<<<1024,256,0,stream>>>(w2c_W, w2cWb, 512*512);
  k_cvt<<<2048,256,0,stream>>>(red_W, redWb, 512*1024);
  k_pad2d<<<128,256,0,stream>>>(const_emb, A80, 80, 512, 512);
  k_pad2d<<<128,256,0,stream>>>(tr_emb,    Atr, 100, 20, 32);
  k_gather_word<<<32768,256,0,stream>>>(word_idx, tag_idx, emb, tag_emb, A_word);

  // ---- XG tables ----
  k_gemm<<<dim3(256,16),256,0,stream>>>(A_word, wWih, XGword, b_word, 320, 2048, 0);
  k_gemm<<<dim3(1,16),256,0,stream>>>(Atr, tWih, tbltr, b_tr, 32, 2048, 0);

  // ---- step 0 for word and transition (A_word dead; trseq slab 0 lives at R+0) ----
  k_gate0<<<256,256,0,stream>>>(XGword, 0, 1, nullptr, 0, c_word, word_h, 512, 0, 128);
  k_gate0<<<256,256,0,stream>>>(tbltr, 2, 0, tr_idx, 512, c_tr, trseq, 512, 0, 128);

  // ---- launch 1: word(1..255) || transition(1..255) ----
  SeqJob jw { word_h, XGword, nullptr, c_word, wWhh, flags + 0*64, 1, 256, 0, 0 };
  SeqJob jt1{ trseq,  tbltr,  tr_idx,  c_tr,   tWhh, flags + 1*64, 1, 256, 1, 1 };
  k_seq2<<<128,256,0,stream>>>(jw, jt1);

  // ---- w2c: c0 = word_h @ w2c_W^T + b ----
  k_gemm<<<dim3(256,4),256,0,stream>>>(word_h, w2cWb, c0, w2c_b, 512, 512, 0);

  // ---- fwd reduce ----
  k_gemm<<<dim3(1,16),256,0,stream>>>(A80, fWih, tbl0, b_fwd, 512, 2048, 0);
  k_gate0<<<32768,256,0,stream>>>(tbl0, 2, 0, lab_idx, 1, c_big, h1, 512, 0, 16384);
  k_lstm_cat<<<dim3(128,16),256,0,stream>>>(h1, c0, fWcat, b_fwd, nullptr, 1, 0, 0, c_big, h2, 512, 0);
  k_lstm_cat<<<dim3(128,16),256,0,stream>>>(h2, c0, fWcat, b_fwd, nullptr, 1, 1, 0, c_big, fb, 1024, 0);
  // ---- bwd reduce ----
  k_gemm<<<dim3(1,16),256,0,stream>>>(A80, bWih, tbl0, b_bwd, 512, 2048, 0);
  k_gate0<<<32768,256,0,stream>>>(tbl0, 2, 0, lab_idx, 1, c_big, h1, 512, 0, 16384);
  k_lstm_cat<<<dim3(128,16),256,0,stream>>>(h1, c0, bWcat, b_bwd, nullptr, 1, 1, 0, c_big, h2, 512, 0);
  k_lstm_cat<<<dim3(128,16),256,0,stream>>>(h2, c0, bWcat, b_bwd, nullptr, 1, 0, 0, c_big, fb, 1024, 512);

  // ---- red = tanh([fh|bh] @ red_W^T + b)  (red @ R+0 over dead tr slabs 0..127) ----
  k_gemm<<<dim3(128,4),256,0,stream>>>(fb, redWb, red, red_b, 1024, 512, 1);

  // ---- XG_con = red @ con_Wih^T + b_con ----
  k_gemm<<<dim3(128,16),256,0,stream>>>(red, cWihp, XG_con, b_con, 512, 2048, 0);

  // ---- con step 0 ----
  k_gate0<<<256,256,0,stream>>>(XG_con, 0, 128, nullptr, 0, c_con, conseq, 512, 0, 128);

  // ---- launch 2: con(1..127) || transition(256..511, slab ring wraps) ----
  SeqJob jc { conseq, XG_con, nullptr, c_con, cWhhp, flags + 2*64, 1,   128, 2, 0 };
  SeqJob jt2{ trseq,  tbltr,  tr_idx,  c_tr,  tWhh,  flags + 3*64, 256, 512, 1, 0 };
  k_seq2<<<128,256,0,stream>>>(jc, jt2);

  // ---- output ----
  k_out<<<3200,256,0,stream>>>(word_h + (size_t)255*65536, trseq + (size_t)255*65536,
                               conseq + (size_t)127*65536, out_W, out_b, (float*)d_out);
}